// Round 3
// baseline (235.664 us; speedup 1.0000x reference)
//
#include <hip/hip_runtime.h>
#include <math.h>

#define S 7
#define NPOS 49      // S*S
#define CCH 256      // channels
#define CSPLIT 4     // channel splits per ROI
#define CPB (CCH / CSPLIT)    // 64 channels per block
#define OUTPB (CPB * NPOS)    // 3136 outputs per block
#define KFULL (OUTPB / 256)   // 12 full iterations
#define KTAIL (OUTPB - KFULL * 256)  // 64 tail outputs
#define DC (256 / NPOS)       // 5
#define DP (256 - DC * NPOS)  // 11

__global__ __launch_bounds__(256) void rroi_align_kernel(
    const float* __restrict__ f0, const float* __restrict__ f1,
    const float* __restrict__ f2, const float* __restrict__ f3,
    const float* __restrict__ rois, const int* __restrict__ levels,
    float* __restrict__ out, int N)
{
    const int bn  = blockIdx.x;          // b*N + n
    const int q   = blockIdx.y;          // channel quarter
    const int b   = bn / N;
    const int tid = threadIdx.x;

    // ---- per-position fused offsets + weights into LDS ----
    __shared__ int4   soff[NPOS];
    __shared__ float4 swt[NPOS];
    __shared__ float  sHW[1];   // unused sentinel to keep LDS small

    // ---- ROI -> rectangle math: only lanes < NPOS need it ----
    const float* r = rois + (size_t)bn * 6;
    const float x = r[0], y = r[1], w = r[2], h = r[3], a = r[4], bb = r[5];

    const int lvl = levels[bn];
    const float* feat; int H, W; float scale;
    switch (lvl) {
      case 0:  feat = f0; H = 256; W = 256; scale = 0.25f;    break;
      case 1:  feat = f1; H = 128; W = 128; scale = 0.125f;   break;
      case 2:  feat = f2; H = 64;  W = 64;  scale = 0.0625f;  break;
      default: feat = f3; H = 32;  W = 32;  scale = 0.03125f; break;
    }

    if (tid < NPOS) {
        // parallelogram -> rectangle (faithful to reference)
        const float v1x = x + a,        v1y = y + 0.5f * h;
        const float v2x = x + 0.5f * w, v2y = y + bb;
        const float v3x = x - a,        v3y = y - 0.5f * h;
        const float v4x = x - 0.5f * w, v4y = y - bb;
        const float d1 = sqrtf((v3x - v1x) * (v3x - v1x) + (v3y - v1y) * (v3y - v1y));
        const float d2 = sqrtf((v4x - v2x) * (v4x - v2x) + (v4y - v2y) * (v4y - v2y));
        const float eps = 1e-6f;
        const bool  cond = d1 > d2;
        const float sA = d1 / (d2 + eps);
        const float sB = d2 / (d1 + eps);
        const float d24x = 0.5f * w, d24y = bb;
        const float d13x = a,        d13y = 0.5f * h;
        const float v2nx = v2x + (sA - 1.f) * d24x, v2ny = v2y + (sA - 1.f) * d24y;
        const float v1nx = v1x + (sB - 1.f) * d13x, v1ny = v1y + (sB - 1.f) * d13y;
        const float v3nx = v3x - (sB - 1.f) * d13x, v3ny = v3y - (sB - 1.f) * d13y;
        const float V0x = cond ? v1x : v1nx, V0y = cond ? v1y : v1ny;
        const float V1x = cond ? v2nx : v2x, V1y = cond ? v2ny : v2y;
        const float V2x = cond ? v3x : v3nx, V2y = cond ? v3y : v3ny;
        const float h_rect = sqrtf((V1x - V0x) * (V1x - V0x) + (V1y - V0y) * (V1y - V0y));
        const float w_rect = sqrtf((V2x - V1x) * (V2x - V1x) + (V2y - V1y) * (V2y - V1y));
        float theta = atan2f(V1y - V2y, V1x - V2x);
        const float HPI = 1.5707963267948966f;
        theta = fminf(fmaxf(theta, -HPI), HPI);

        const int iy = tid / S, ix = tid - iy * S;
        const float tI = (float)ix / (float)(S - 1) - 0.5f;  // column -> x
        const float tJ = (float)iy / (float)(S - 1) - 0.5f;  // row    -> y
        const float c_ = cosf(theta), s_ = sinf(theta);
        const float x_r = x * scale, y_r = y * scale;
        const float gx = (w_rect * scale) * tI;
        const float gy = (h_rect * scale) * tJ;
        const float rx =  gx * c_ + gy * s_ + x_r;
        const float ry = -gx * s_ + gy * c_ + y_r;
        // faithful double-scale + align_corners normalize/unmap chain
        const float gxn = rx * scale / (float)(W - 1) * 2.f - 1.f;
        const float gyn = ry * scale / (float)(H - 1) * 2.f - 1.f;
        const float px = ((gxn + 1.f) * (float)W - 1.f) * 0.5f;
        const float py = ((gyn + 1.f) * (float)H - 1.f) * 0.5f;
        const float x0f = floorf(px), y0f = floorf(py);
        const float wx = px - x0f, wy = py - y0f;
        int x0 = (int)x0f; x0 = min(max(x0, 0), W - 1);
        int y0 = (int)y0f; y0 = min(max(y0, 0), H - 1);
        const int x1 = min(x0 + 1, W - 1);
        const int y1 = min(y0 + 1, W - 1 < H - 1 ? H - 1 : H - 1); // y clamp
        soff[tid] = make_int4(y0 * W + x0, y0 * W + x1,
                              y1 * W + x0, y1 * W + x1);
        swt[tid]  = make_float4((1.f - wx) * (1.f - wy),
                                wx         * (1.f - wy),
                                (1.f - wx) * wy,
                                wx         * wy);
    }
    __syncthreads();

    // ---- main loop: 64 channels, coalesced stores ----
    const size_t plane = (size_t)H * W;
    const float* fb = feat + ((size_t)b * CCH + (size_t)q * CPB) * plane;
    float* ob = out + (size_t)bn * CCH * NPOS + (size_t)q * OUTPB;

    int c   = tid / NPOS;        // one div, outside loop
    int pos = tid - c * NPOS;

    #pragma unroll 4
    for (int k = 0; k < KFULL; ++k) {
        const int4   o  = soff[pos];
        const float4 wt = swt[pos];
        const float* fc = fb + (size_t)c * plane;
        const float v00 = fc[o.x];
        const float v01 = fc[o.y];
        const float v10 = fc[o.z];
        const float v11 = fc[o.w];
        const float val = fmaf(v00, wt.x,
                          fmaf(v01, wt.y,
                          fmaf(v10, wt.z,
                               v11 * wt.w)));
        __builtin_nontemporal_store(val, &ob[k * 256 + tid]);
        // incremental (c, pos) update: idx advances by 256 = DC*49 + DP
        pos += DP; c += DC;
        if (pos >= NPOS) { pos -= NPOS; ++c; }
    }
    // tail: idx in [3072, 3136)
    if (tid < KTAIL) {
        const int idx = KFULL * 256 + tid;
        const int cc  = idx / NPOS;
        const int pp  = idx - cc * NPOS;
        const int4   o  = soff[pp];
        const float4 wt = swt[pp];
        const float* fc = fb + (size_t)cc * plane;
        const float v00 = fc[o.x];
        const float v01 = fc[o.y];
        const float v10 = fc[o.z];
        const float v11 = fc[o.w];
        const float val = fmaf(v00, wt.x,
                          fmaf(v01, wt.y,
                          fmaf(v10, wt.z,
                               v11 * wt.w)));
        __builtin_nontemporal_store(val, &ob[idx]);
    }
}

extern "C" void kernel_launch(void* const* d_in, const int* in_sizes, int n_in,
                              void* d_out, int out_size, void* d_ws, size_t ws_size,
                              hipStream_t stream) {
    const float* f0   = (const float*)d_in[0];
    const float* f1   = (const float*)d_in[1];
    const float* f2   = (const float*)d_in[2];
    const float* f3   = (const float*)d_in[3];
    const float* rois = (const float*)d_in[4];
    const int*   lev  = (const int*)d_in[5];
    float* out = (float*)d_out;

    const int total_bn = in_sizes[5];                 // B*N
    const int B = in_sizes[0] / (CCH * 256 * 256);    // f0 = [B,256,256,256]
    const int N = total_bn / B;

    dim3 grid(total_bn, CSPLIT);
    rroi_align_kernel<<<grid, 256, 0, stream>>>(f0, f1, f2, f3, rois, lev, out, N);
}

// Round 4
// 228.189 us; speedup vs baseline: 1.0328x; 1.0328x over previous
//
#include <hip/hip_runtime.h>
#include <math.h>

#define S 7
#define NPOS 49      // S*S
#define CCH 256      // channels
#define CSPLIT 4     // channel splits per ROI
#define CPB (CCH / CSPLIT)    // 64 channels per block
#define OUTPB (CPB * NPOS)    // 3136 outputs per block
#define KFULL (OUTPB / 256)   // 12 full iterations
#define KTAIL (OUTPB - KFULL * 256)  // 64 tail outputs
#define DC (256 / NPOS)       // 5
#define DP (256 - DC * NPOS)  // 11

__global__ __launch_bounds__(256) void rroi_align_kernel(
    const float* __restrict__ f0, const float* __restrict__ f1,
    const float* __restrict__ f2, const float* __restrict__ f3,
    const float* __restrict__ rois, const int* __restrict__ levels,
    float* __restrict__ out, int N)
{
    const int bn  = blockIdx.x;          // b*N + n
    const int q   = blockIdx.y;          // channel quarter
    const int b   = bn / N;
    const int tid = threadIdx.x;

    // per-position: row-pair base offsets (x-merged) + folded weights
    __shared__ int2   soff[NPOS];   // .x = row y0 base, .y = row y1 base
    __shared__ float4 swt[NPOS];    // w00,w01,w10,w11 (select folded in)

    const float* r = rois + (size_t)bn * 6;
    const float x = r[0], y = r[1], w = r[2], h = r[3], a = r[4], bb = r[5];

    const int lvl = levels[bn];
    const float* feat; int H, W; float scale;
    switch (lvl) {
      case 0:  feat = f0; H = 256; W = 256; scale = 0.25f;    break;
      case 1:  feat = f1; H = 128; W = 128; scale = 0.125f;   break;
      case 2:  feat = f2; H = 64;  W = 64;  scale = 0.0625f;  break;
      default: feat = f3; H = 32;  W = 32;  scale = 0.03125f; break;
    }

    if (tid < NPOS) {
        // parallelogram -> rectangle (faithful to reference)
        const float v1x = x + a,        v1y = y + 0.5f * h;
        const float v2x = x + 0.5f * w, v2y = y + bb;
        const float v3x = x - a,        v3y = y - 0.5f * h;
        const float v4x = x - 0.5f * w, v4y = y - bb;
        const float d1 = sqrtf((v3x - v1x) * (v3x - v1x) + (v3y - v1y) * (v3y - v1y));
        const float d2 = sqrtf((v4x - v2x) * (v4x - v2x) + (v4y - v2y) * (v4y - v2y));
        const float eps = 1e-6f;
        const bool  cond = d1 > d2;
        const float sA = d1 / (d2 + eps);
        const float sB = d2 / (d1 + eps);
        const float d24x = 0.5f * w, d24y = bb;
        const float d13x = a,        d13y = 0.5f * h;
        const float v2nx = v2x + (sA - 1.f) * d24x, v2ny = v2y + (sA - 1.f) * d24y;
        const float v1nx = v1x + (sB - 1.f) * d13x, v1ny = v1y + (sB - 1.f) * d13y;
        const float v3nx = v3x - (sB - 1.f) * d13x, v3ny = v3y - (sB - 1.f) * d13y;
        const float V0x = cond ? v1x : v1nx, V0y = cond ? v1y : v1ny;
        const float V1x = cond ? v2nx : v2x, V1y = cond ? v2ny : v2y;
        const float V2x = cond ? v3x : v3nx, V2y = cond ? v3y : v3ny;
        const float h_rect = sqrtf((V1x - V0x) * (V1x - V0x) + (V1y - V0y) * (V1y - V0y));
        const float w_rect = sqrtf((V2x - V1x) * (V2x - V1x) + (V2y - V1y) * (V2y - V1y));
        float theta = atan2f(V1y - V2y, V1x - V2x);
        const float HPI = 1.5707963267948966f;
        theta = fminf(fmaxf(theta, -HPI), HPI);

        const int iy = tid / S, ix = tid - iy * S;
        const float tI = (float)ix / (float)(S - 1) - 0.5f;  // column -> x
        const float tJ = (float)iy / (float)(S - 1) - 0.5f;  // row    -> y
        const float c_ = cosf(theta), s_ = sinf(theta);
        const float x_r = x * scale, y_r = y * scale;
        const float gx = (w_rect * scale) * tI;
        const float gy = (h_rect * scale) * tJ;
        const float rx =  gx * c_ + gy * s_ + x_r;
        const float ry = -gx * s_ + gy * c_ + y_r;
        // faithful double-scale + align_corners normalize/unmap chain
        const float gxn = rx * scale / (float)(W - 1) * 2.f - 1.f;
        const float gyn = ry * scale / (float)(H - 1) * 2.f - 1.f;
        const float px = ((gxn + 1.f) * (float)W - 1.f) * 0.5f;
        const float py = ((gyn + 1.f) * (float)H - 1.f) * 0.5f;
        const float x0f = floorf(px), y0f = floorf(py);
        const float wx = px - x0f, wy = py - y0f;
        int x0 = (int)x0f; x0 = min(max(x0, 0), W - 1);
        int y0 = (int)y0f; y0 = min(max(y0, 0), H - 1);
        const int y1 = min(y0 + 1, H - 1);

        float w00 = (1.f - wx) * (1.f - wy);
        float w01 = wx         * (1.f - wy);
        float w10 = (1.f - wx) * wy;
        float w11 = wx         * wy;
        // x-pair merge: load float2 at xbase covering {x0,x1}. Right-edge
        // clamp (x0==W-1 -> x1==x0): shift base to W-2, fold select into
        // weights so pair.y carries both contributions. Values bit-identical.
        int xbase = x0;
        if (x0 == W - 1) {
            xbase = W - 2;
            w01 += w00;  w00 = 0.f;     // v00 == v01 == pair.y
            w11 += w10;  w10 = 0.f;
        }
        soff[tid] = make_int2(y0 * W + xbase, y1 * W + xbase);
        swt[tid]  = make_float4(w00, w01, w10, w11);
    }
    __syncthreads();

    // ---- main loop: 64 channels, coalesced stores ----
    const size_t plane = (size_t)H * W;
    const float* fb = feat + ((size_t)b * CCH + (size_t)q * CPB) * plane;
    float* ob = out + (size_t)bn * CCH * NPOS + (size_t)q * OUTPB;

    int c   = tid / NPOS;        // one div, outside loop
    int pos = tid - c * NPOS;

    #pragma unroll 4
    for (int k = 0; k < KFULL; ++k) {
        const int2   o  = soff[pos];
        const float4 wt = swt[pos];
        const float* fc = fb + (size_t)c * plane;
        float2 p0, p1;                       // {v00,v01}, {v10,v11}
        __builtin_memcpy(&p0, fc + o.x, 8);  // dwordx2 if unaligned-ok, else 2x dword
        __builtin_memcpy(&p1, fc + o.y, 8);
        const float val = fmaf(p0.x, wt.x,
                          fmaf(p0.y, wt.y,
                          fmaf(p1.x, wt.z,
                               p1.y * wt.w)));
        __builtin_nontemporal_store(val, &ob[k * 256 + tid]);
        pos += DP; c += DC;
        if (pos >= NPOS) { pos -= NPOS; ++c; }
    }
    // tail: idx in [3072, 3136)
    if (tid < KTAIL) {
        const int idx = KFULL * 256 + tid;
        const int cc  = idx / NPOS;
        const int pp  = idx - cc * NPOS;
        const int2   o  = soff[pp];
        const float4 wt = swt[pp];
        const float* fc = fb + (size_t)cc * plane;
        float2 p0, p1;
        __builtin_memcpy(&p0, fc + o.x, 8);
        __builtin_memcpy(&p1, fc + o.y, 8);
        const float val = fmaf(p0.x, wt.x,
                          fmaf(p0.y, wt.y,
                          fmaf(p1.x, wt.z,
                               p1.y * wt.w)));
        __builtin_nontemporal_store(val, &ob[idx]);
    }
}

extern "C" void kernel_launch(void* const* d_in, const int* in_sizes, int n_in,
                              void* d_out, int out_size, void* d_ws, size_t ws_size,
                              hipStream_t stream) {
    const float* f0   = (const float*)d_in[0];
    const float* f1   = (const float*)d_in[1];
    const float* f2   = (const float*)d_in[2];
    const float* f3   = (const float*)d_in[3];
    const float* rois = (const float*)d_in[4];
    const int*   lev  = (const int*)d_in[5];
    float* out = (float*)d_out;

    const int total_bn = in_sizes[5];                 // B*N
    const int B = in_sizes[0] / (CCH * 256 * 256);    // f0 = [B,256,256,256]
    const int N = total_bn / B;

    dim3 grid(total_bn, CSPLIT);
    rroi_align_kernel<<<grid, 256, 0, stream>>>(f0, f1, f2, f3, rois, lev, out, N);
}